// Round 16
// baseline (82.269 us; speedup 1.0000x reference)
//
#include <hip/hip_runtime.h>
#include <hip/hip_bf16.h>
#include <math.h>

#define HH 128
#define NN 64
#define LL 4096
#define BB 8
#define NFFT 8192
#define KSTR 4160  // per-pair stride (in float4) of interleaved K spectrum

// stage1 grid partitions (r12 winner, unchanged)
#define CAU_BLOCKS 1024   // 128 h x 8 l-blocks; each thread does 2 l-points
#define TRU_BLOCKS 4096   // 8 b x 4 h-tiles x 128 l-tiles (32x32), packed float2 out
#define SKP_BLOCKS 8192   // 4 rows/block (1 row per 64-lane wave) — backfill

__device__ __forceinline__ float2 cmul(float2 a, float2 b) {
    return make_float2(a.x * b.x - a.y * b.y, a.x * b.y + a.y * b.x);
}
__device__ __forceinline__ float2 cadd(float2 a, float2 b) {
    return make_float2(a.x + b.x, a.y + b.y);
}
__device__ __forceinline__ float2 csub(float2 a, float2 b) {
    return make_float2(a.x - b.x, a.y - b.y);
}
__device__ __forceinline__ int brev13(int x) { return (int)(__brev((unsigned)x) >> 19); }
__device__ __forceinline__ int kkmap(int t) {
    return (t < 4096) ? (((t & 63) << 6) | (t >> 6)) : 4096;
}
// LDS bank swizzle: bijective within 16-elem groups, keeps 8B alignment,
// swz(v+4096)==swz(v)+4096. Makes every FFT pass stride conflict-free.
__device__ __forceinline__ int swz(int v) { return v ^ ((v >> 4) & 15); }

// Twiddle via HW sin/cos (REVOLUTIONS, arg in [0,0.5) -> no range reduction).
__device__ __forceinline__ float2 twid(float rev, float sg) {
    return make_float2(__builtin_amdgcn_cosf(rev), sg * __builtin_amdgcn_sinf(rev));
}

// ---- Fused radix-8 passes (three radix-2 stages; bitrev semantics preserved) ----

template <int M>
__device__ __forceinline__ void dif_f8(float2* d, int N, int tid, int nt, float sg) {
    const float inv2m = 1.0f / (2.0f * (float)M);
    const float inv4m = 1.0f / (4.0f * (float)M);
    const float inv8m = 1.0f / (8.0f * (float)M);
    const float s2 = 0.70710678118654752f;
    for (int q = tid; q < (N >> 3); q += nt) {
        int j = q & (M - 1);
        int i0 = ((q & ~(M - 1)) << 3) + j;
        float2 x0 = d[swz(i0)],         x1 = d[swz(i0 + M)],
               x2 = d[swz(i0 + 2 * M)], x3 = d[swz(i0 + 3 * M)],
               x4 = d[swz(i0 + 4 * M)], x5 = d[swz(i0 + 5 * M)],
               x6 = d[swz(i0 + 6 * M)], x7 = d[swz(i0 + 7 * M)];
        float jf = (float)j;
        float2 w8 = twid(jf * inv8m, sg);
        float2 w4 = twid(jf * inv4m, sg);
        float2 w2 = twid(jf * inv2m, sg);
        float2 e1 = make_float2(s2, sg * s2);
        float2 e3 = make_float2(-s2, sg * s2);
        float2 y0 = cadd(x0, x4), y1 = cadd(x1, x5), y2 = cadd(x2, x6), y3 = cadd(x3, x7);
        float2 t0 = csub(x0, x4), t1 = csub(x1, x5), t2 = csub(x2, x6), t3 = csub(x3, x7);
        float2 w8i = make_float2(-sg * w8.y, sg * w8.x);
        float2 z0 = cmul(w8, t0);
        float2 z1 = cmul(cmul(w8, e1), t1);
        float2 z2 = cmul(w8i, t2);
        float2 z3 = cmul(cmul(w8, e3), t3);
        {
            float2 a0 = cadd(y0, y2);
            float2 a2 = cmul(w4, csub(y0, y2));
            float2 a1 = cadd(y1, y3);
            float2 t = cmul(w4, csub(y1, y3));
            float2 a3 = make_float2(-sg * t.y, sg * t.x);
            d[swz(i0)]         = cadd(a0, a1);
            d[swz(i0 + M)]     = cmul(w2, csub(a0, a1));
            d[swz(i0 + 2 * M)] = cadd(a2, a3);
            d[swz(i0 + 3 * M)] = cmul(w2, csub(a2, a3));
        }
        {
            float2 a0 = cadd(z0, z2);
            float2 a2 = cmul(w4, csub(z0, z2));
            float2 a1 = cadd(z1, z3);
            float2 t = cmul(w4, csub(z1, z3));
            float2 a3 = make_float2(-sg * t.y, sg * t.x);
            d[swz(i0 + 4 * M)] = cadd(a0, a1);
            d[swz(i0 + 5 * M)] = cmul(w2, csub(a0, a1));
            d[swz(i0 + 6 * M)] = cadd(a2, a3);
            d[swz(i0 + 7 * M)] = cmul(w2, csub(a2, a3));
        }
    }
    __syncthreads();
}

template <int M>
__device__ __forceinline__ void dit_f8(float2* d, int N, int tid, int nt, float sg) {
    const float inv2m = 1.0f / (2.0f * (float)M);
    const float inv4m = 1.0f / (4.0f * (float)M);
    const float inv8m = 1.0f / (8.0f * (float)M);
    const float s2 = 0.70710678118654752f;
    for (int q = tid; q < (N >> 3); q += nt) {
        int j = q & (M - 1);
        int i0 = ((q & ~(M - 1)) << 3) + j;
        float2 x0 = d[swz(i0)],         x1 = d[swz(i0 + M)],
               x2 = d[swz(i0 + 2 * M)], x3 = d[swz(i0 + 3 * M)],
               x4 = d[swz(i0 + 4 * M)], x5 = d[swz(i0 + 5 * M)],
               x6 = d[swz(i0 + 6 * M)], x7 = d[swz(i0 + 7 * M)];
        float jf = (float)j;
        float2 wA = twid(jf * inv2m, sg);
        float2 wB = twid(jf * inv4m, sg);
        float2 wC = twid(jf * inv8m, sg);
        float2 t;
        t = cmul(wA, x1); float2 b0 = cadd(x0, t), b1 = csub(x0, t);
        t = cmul(wA, x3); float2 b2 = cadd(x2, t), b3 = csub(x2, t);
        t = cmul(wA, x5); float2 b4 = cadd(x4, t), b5 = csub(x4, t);
        t = cmul(wA, x7); float2 b6 = cadd(x6, t), b7 = csub(x6, t);
        float2 wBi = make_float2(-sg * wB.y, sg * wB.x);
        t = cmul(wB, b2);  float2 c0 = cadd(b0, t), c2 = csub(b0, t);
        t = cmul(wBi, b3); float2 c1 = cadd(b1, t), c3 = csub(b1, t);
        t = cmul(wB, b6);  float2 c4 = cadd(b4, t), c6 = csub(b4, t);
        t = cmul(wBi, b7); float2 c5 = cadd(b5, t), c7 = csub(b5, t);
        float2 e1 = make_float2(s2, sg * s2);
        float2 e3 = make_float2(-s2, sg * s2);
        float2 w1 = cmul(wC, e1);
        float2 w2_ = make_float2(-sg * wC.y, sg * wC.x);
        float2 w3 = cmul(wC, e3);
        t = cmul(wC, c4);  d[swz(i0)]         = cadd(c0, t); d[swz(i0 + 4 * M)] = csub(c0, t);
        t = cmul(w1, c5);  d[swz(i0 + M)]     = cadd(c1, t); d[swz(i0 + 5 * M)] = csub(c1, t);
        t = cmul(w2_, c6); d[swz(i0 + 2 * M)] = cadd(c2, t); d[swz(i0 + 6 * M)] = csub(c2, t);
        t = cmul(w3, c7);  d[swz(i0 + 3 * M)] = cadd(c3, t); d[swz(i0 + 7 * M)] = csub(c3, t);
    }
    __syncthreads();
}

// Stage 1 (r12 winner, unchanged): cauchy 2pt (v11-real) ++ transpose-packed ++ skip.
__global__ __launch_bounds__(256, 8) void stage1_kernel(
    const float* __restrict__ u,
    const float* __restrict__ B_ri, const float* __restrict__ C_ri,
    const float* __restrict__ D,
    const float* __restrict__ Lambda_ri, const float* __restrict__ P_ri,
    const float* __restrict__ step,
    float2* __restrict__ at_g, float2* __restrict__ ut2, float* __restrict__ skip) {
    __shared__ float4 smem4[264];
    const int bid = blockIdx.x;
    const int tid = threadIdx.x;

    if (bid < CAU_BLOCKS) {
        float* v11f = (float*)(smem4 + 128);  // [64]
        const int h = bid >> 3;
        if (tid < NN) {
            int n = tid;
            float2 C = ((const float2*)C_ri)[h * NN + n];
            float2 Bv = ((const float2*)B_ri)[h * NN + n];
            float2 P = ((const float2*)P_ri)[h * NN + n];
            float2 lam = ((const float2*)Lambda_ri)[h * NN + n];
            float2 Cc = make_float2(C.x, -C.y);
            float2 Pc = make_float2(P.x, -P.y);
            float2 v00 = cmul(Cc, Bv);
            float2 v01 = cmul(Cc, P);
            float2 v10 = cmul(Pc, Bv);
            smem4[2 * n + 0] = make_float4(lam.x, lam.y, v00.x, v00.y);
            smem4[2 * n + 1] = make_float4(v01.x, v01.y, v10.x, v10.y);
            v11f[n] = P.x * P.x + P.y * P.y;
        }
        __syncthreads();

        const int lbase = ((bid & 7) << 8) | tid;  // [0, 2048)
        const float two_over_step = 2.0f / step[0];
        float gr[2], gi[2], ccx[2], ccy[2];
#pragma unroll
        for (int p = 0; p < 2; ++p) {
            int l = lbase + p * 2048;
            // libm sincosf: at l=2048 the fp32-pi inexactness keeps 1+z away from
            // exactly 0 (matches reference). DO NOT replace with HW sin/cos.
            double th = -6.283185307179586476925286766559 * (double)l / (double)LL;
            float sn, cs;
            sincosf((float)th, &sn, &cs);
            float dr = 1.0f + cs, di = sn;
            float inv = __builtin_amdgcn_rcpf(dr * dr + di * di);
            float nr = 1.0f - cs, ni = -sn;
            gr[p] = two_over_step * (nr * dr + ni * di) * inv;
            gi[p] = two_over_step * (ni * dr - nr * di) * inv;
            ccx[p] = 2.0f * dr * inv;
            ccy[p] = -2.0f * di * inv;
        }

        float2 k00[2], k01[2], k10[2], k11[2];
#pragma unroll
        for (int p = 0; p < 2; ++p) {
            k00[p] = make_float2(0.f, 0.f);
            k01[p] = make_float2(0.f, 0.f);
            k10[p] = make_float2(0.f, 0.f);
            k11[p] = make_float2(0.f, 0.f);
        }
#pragma unroll 4
        for (int n = 0; n < NN; ++n) {
            float4 tA = smem4[2 * n + 0];
            float4 tB = smem4[2 * n + 1];
            float w11 = v11f[n];
#pragma unroll
            for (int p = 0; p < 2; ++p) {
                float ar = gr[p] - tA.x, ai = gi[p] - tA.y;
                float id = __builtin_amdgcn_rcpf(ar * ar + ai * ai);
                float2 r = make_float2(ar * id, -ai * id);
                k00[p] = cadd(k00[p], cmul(make_float2(tA.z, tA.w), r));
                k01[p] = cadd(k01[p], cmul(make_float2(tB.x, tB.y), r));
                k10[p] = cadd(k10[p], cmul(make_float2(tB.z, tB.w), r));
                k11[p].x += w11 * r.x;
                k11[p].y += w11 * r.y;
            }
        }
#pragma unroll
        for (int p = 0; p < 2; ++p) {
            float wr = 1.0f + k11[p].x, wi = k11[p].y;
            float iw = __builtin_amdgcn_rcpf(wr * wr + wi * wi);
            float2 winv = make_float2(wr * iw, -wi * iw);
            float2 t = cmul(cmul(k01[p], winv), k10[p]);
            float2 at = cmul(make_float2(ccx[p], ccy[p]),
                             make_float2(k00[p].x - t.x, k00[p].y - t.y));
            at_g[(size_t)h * LL + lbase + p * 2048] = at;
        }
    } else if (bid < CAU_BLOCKS + TRU_BLOCKS) {
        float* tile = (float*)smem4;  // [32][33]
        int tb = bid - CAU_BLOCKS;
        int b = tb >> 9;
        int hq = (tb >> 7) & 3;
        int h0 = hq * 32;
        int l0 = (tb & 127) * 32;
        int tx = tid & 31, ty = tid >> 5;
        const float* up = u + (size_t)b * LL * HH;
        for (int i = ty; i < 32; i += 8)
            tile[i * 33 + tx] = up[(size_t)(l0 + i) * HH + h0 + tx];
        __syncthreads();
        float2* utp = ut2 + (size_t)b * 64 * LL;
#pragma unroll
        for (int i = ty; i < 16; i += 8) {
            int c = (h0 >> 1) + i;
            float2 v = make_float2(tile[tx * 33 + 2 * i], tile[tx * 33 + 2 * i + 1]);
            utp[(size_t)c * LL + l0 + tx] = v;
        }
    } else {
        int sb = bid - (CAU_BLOCKS + TRU_BLOCKS);
        int wid = tid >> 6, lane = tid & 63;
        int row = sb * 4 + wid;
        const float* ur = u + (size_t)row * HH;
        float v = ur[lane] * D[lane] + ur[lane + 64] * D[lane + 64];
        for (int off = 32; off > 0; off >>= 1) v += __shfl_down(v, off, 64);
        if (lane == 0) skip[row] = v;
    }
}

// Kernel A2: per h — scatter-load at -> IFFT4096 (dit_f8 x4) -> fused
// {scale+pad+head-r2} -> FFT8192 (dif_f8 x4) -> interleaved K01 store:
// K01[c][t] = {K_{2c}(kk(t)), K_{2c+1}(kk(t))} as float4 (h even -> .xy, odd -> .zw).
__global__ __launch_bounds__(1024) void kfreq_kernel(const float2* __restrict__ at_g,
                                                     float2* __restrict__ K01v) {
    __shared__ float2 sm[NFFT];  // 64 KB
    const int h = blockIdx.x;
    const int tid = threadIdx.x;
    const float2* ap = at_g + (size_t)h * LL;
#pragma unroll
    for (int it = 0; it < 4; ++it) {
        int t = tid + it * 1024;
        int l = ((t & 63) << 6) | (t >> 6);          // low6<->high6 swap
        sm[swz((int)(__brev((unsigned)l) >> 20))] = ap[l];
    }
    __syncthreads();

    dit_f8<1>(sm, 4096, tid, 1024, +1.f);
    dit_f8<8>(sm, 4096, tid, 1024, +1.f);
    dit_f8<64>(sm, 4096, tid, 1024, +1.f);
    dit_f8<512>(sm, 4096, tid, 1024, +1.f);

    const float inv8192 = 1.0f / 8192.0f;
    for (int t = tid; t < 4096; t += 1024) {
        float kv = sm[swz(t)].x * (1.0f / 4096.0f);
        float2 w = twid((float)t * inv8192, -1.f);
        sm[swz(t)] = make_float2(kv, 0.f);
        sm[swz(t + 4096)] = make_float2(kv * w.x, kv * w.y);
    }
    __syncthreads();

    dif_f8<512>(sm, 8192, tid, 1024, -1.f);
    dif_f8<64>(sm, 8192, tid, 1024, -1.f);
    dif_f8<8>(sm, 8192, tid, 1024, -1.f);
    dif_f8<1>(sm, 8192, tid, 1024, -1.f);

    // interleaved store: float2 view, pair slot = 2*t + (h&1); conv reads float4.
    float2* kp = K01v + (size_t)(h >> 1) * (2 * KSTR) + (h & 1);
    for (int t = tid; t <= 4096; t += 1024)
        kp[2 * t] = sm[swz(brev13(kkmap(t)))];
}

// Kernel C: two-for-one conv — packed float2 input, interleaved float4 K,
// DIRECT scatter store to y[B,L,H] with fused skip add (transY eliminated).
// Block id mapping bid = (c&7)*64 + b*8 + (c>>3): the 8 c-blocks sharing c>>3
// (which co-write each 64B line of y) share bid%8 -> same XCD L2, so partial
// 8B line writes merge in L2 and evict as full lines.
__global__ __launch_bounds__(1024) void conv_fft_kernel(const float2* __restrict__ ut2,
                                                        const float4* __restrict__ K01,
                                                        const float* __restrict__ skip,
                                                        float* __restrict__ y) {
    __shared__ float2 sm[NFFT];  // 64 KB
    const int bid = blockIdx.x;
    const int b = (bid >> 3) & 7;
    const int c = (bid >> 6) + ((bid & 7) << 3);
    const int tid = threadIdx.x;
    const float2* up2 = ut2 + ((size_t)b * 64 + c) * LL;
    const float inv8192 = 1.0f / 8192.0f;

    // fused load + head radix-2 DIF stage (upper half of input is zero)
    for (int i = tid; i < 4096; i += 1024) {
        float2 a = up2[i];
        float2 w = twid((float)i * inv8192, -1.f);
        sm[swz(i)] = a;
        sm[swz(i + 4096)] = cmul(w, a);
    }
    __syncthreads();

    dif_f8<512>(sm, 8192, tid, 1024, -1.f);
    dif_f8<64>(sm, 8192, tid, 1024, -1.f);
    dif_f8<8>(sm, 8192, tid, 1024, -1.f);
    dif_f8<1>(sm, 8192, tid, 1024, -1.f);

    // Pointwise in bitrev order; each thread-iteration owns conjugate pair (k, N-k).
    const float4* kc = K01 + (size_t)c * KSTR;
    for (int t = tid; t <= 4096; t += 1024) {
        int kk = kkmap(t);
        bool self = (kk == 0) || (kk == 4096);
        int p = swz(brev13(kk));
        int q = self ? p : swz(brev13(NFFT - kk));
        float4 kv = kc[t];
        float2 K0 = make_float2(kv.x, kv.y);
        float2 K1 = make_float2(kv.z, kv.w);
        float2 Zp = sm[p];
        float2 Zq = sm[q];
        float2 U0 = make_float2(0.5f * (Zp.x + Zq.x), 0.5f * (Zp.y - Zq.y));
        float2 U1 = make_float2(0.5f * (Zp.y + Zq.y), 0.5f * (Zq.x - Zp.x));
        float2 A = cmul(U0, K0);
        float2 C = cmul(U1, K1);
        sm[p] = make_float2(A.x - C.y, A.y + C.x);             // W[k]   = A + iC
        if (!self) sm[q] = make_float2(A.x + C.y, C.x - A.y);  // W[N-k] = conj(A - iC)
    }
    __syncthreads();

    dit_f8<1>(sm, 8192, tid, 1024, +1.f);
    dit_f8<8>(sm, 8192, tid, 1024, +1.f);
    dit_f8<64>(sm, 8192, tid, 1024, +1.f);
    dit_f8<512>(sm, 8192, tid, 1024, +1.f);

    // fused tail radix-2 DIT stage + 1/N scale + skip add + direct [B,L,H] store
    float* yb = y + (size_t)b * LL * HH + 2 * c;
    const float* skb = skip + (size_t)b * LL;
    const float invN = 1.0f / (float)NFFT;
    for (int x = tid; x < 4096; x += 1024) {
        float2 w = twid((float)x * inv8192, +1.f);
        float2 a = sm[swz(x)];
        float2 bb = cmul(w, sm[swz(x + 4096)]);
        float sk = skb[x];
        *(float2*)&yb[(size_t)x * HH] =
            make_float2((a.x + bb.x) * invN + sk, (a.y + bb.y) * invN + sk);
    }
}

extern "C" void kernel_launch(void* const* d_in, const int* in_sizes, int n_in,
                              void* d_out, int out_size, void* d_ws, size_t ws_size,
                              hipStream_t stream) {
    const float* u = (const float*)d_in[0];
    const float* B_ri = (const float*)d_in[1];
    const float* C_ri = (const float*)d_in[2];
    const float* D = (const float*)d_in[3];
    const float* Lambda_ri = (const float*)d_in[4];
    const float* P_ri = (const float*)d_in[5];
    const float* step = (const float*)d_in[6];
    float* out = (float*)d_out;

    char* ws = (char*)d_ws;
    float4* K01 = (float4*)ws;                              // 64*4160*16 ≈ 4.3 MB @ 0
    float* skip = (float*)(ws + (size_t)6 * 1024 * 1024);   // 128 KB @ 6 MB
    float2* ut2 = (float2*)(ws + (size_t)8 * 1024 * 1024);  // 16 MB @ 8 MB
    float2* at_g = (float2*)(ws + (size_t)24 * 1024 * 1024);// 4 MB @ 24 MB

    stage1_kernel<<<dim3(CAU_BLOCKS + TRU_BLOCKS + SKP_BLOCKS), dim3(256), 0, stream>>>(
        u, B_ri, C_ri, D, Lambda_ri, P_ri, step, at_g, ut2, skip);
    kfreq_kernel<<<dim3(HH), dim3(1024), 0, stream>>>(at_g, (float2*)K01);
    conv_fft_kernel<<<dim3(BB * HH / 2), dim3(1024), 0, stream>>>(ut2, K01, skip, out);
}

// Round 17
// 79.409 us; speedup vs baseline: 1.0360x; 1.0360x over previous
//
#include <hip/hip_runtime.h>
#include <hip/hip_bf16.h>
#include <hip/hip_fp16.h>
#include <math.h>

#define HH 128
#define NN 64
#define LL 4096
#define BB 8
#define NFFT 8192
#define KSTR 4160  // per-h stride of permuted K spectrum (4097 used, padded)

// stage1 grid partitions, dispatch order: cauchy (critical path) -> transpose -> skip
#define CAU_BLOCKS 1024   // 128 h x 8 l-blocks; each thread does 2 l-points
#define TRU_BLOCKS 4096   // 8 b x 4 h-tiles x 128 l-tiles (32x32), packed float2 out
#define SKP_BLOCKS 8192   // 4 rows/block (1 row per 64-lane wave) — backfill

__device__ __forceinline__ float2 cmul(float2 a, float2 b) {
    return make_float2(a.x * b.x - a.y * b.y, a.x * b.y + a.y * b.x);
}
__device__ __forceinline__ float2 cadd(float2 a, float2 b) {
    return make_float2(a.x + b.x, a.y + b.y);
}
__device__ __forceinline__ float2 csub(float2 a, float2 b) {
    return make_float2(a.x - b.x, a.y - b.y);
}
__device__ __forceinline__ int brev13(int x) { return (int)(__brev((unsigned)x) >> 19); }
__device__ __forceinline__ int kkmap(int t) {
    return (t < 4096) ? (((t & 63) << 6) | (t >> 6)) : 4096;
}
// LDS bank swizzle: bijective within 16-elem groups, keeps 8B alignment,
// swz(v+4096)==swz(v)+4096. Makes every FFT pass stride conflict-free.
__device__ __forceinline__ int swz(int v) { return v ^ ((v >> 4) & 15); }

// Twiddle via HW sin/cos (REVOLUTIONS, arg in [0,0.5) -> no range reduction).
__device__ __forceinline__ float2 twid(float rev, float sg) {
    return make_float2(__builtin_amdgcn_cosf(rev), sg * __builtin_amdgcn_sinf(rev));
}

// ---- Fused radix-8 passes (three radix-2 stages; bitrev semantics preserved) ----

template <int M>
__device__ __forceinline__ void dif_f8(float2* d, int N, int tid, int nt, float sg) {
    const float inv2m = 1.0f / (2.0f * (float)M);
    const float inv4m = 1.0f / (4.0f * (float)M);
    const float inv8m = 1.0f / (8.0f * (float)M);
    const float s2 = 0.70710678118654752f;
    for (int q = tid; q < (N >> 3); q += nt) {
        int j = q & (M - 1);
        int i0 = ((q & ~(M - 1)) << 3) + j;
        float2 x0 = d[swz(i0)],         x1 = d[swz(i0 + M)],
               x2 = d[swz(i0 + 2 * M)], x3 = d[swz(i0 + 3 * M)],
               x4 = d[swz(i0 + 4 * M)], x5 = d[swz(i0 + 5 * M)],
               x6 = d[swz(i0 + 6 * M)], x7 = d[swz(i0 + 7 * M)];
        float jf = (float)j;
        float2 w8 = twid(jf * inv8m, sg);
        float2 w4 = twid(jf * inv4m, sg);
        float2 w2 = twid(jf * inv2m, sg);
        float2 e1 = make_float2(s2, sg * s2);
        float2 e3 = make_float2(-s2, sg * s2);
        float2 y0 = cadd(x0, x4), y1 = cadd(x1, x5), y2 = cadd(x2, x6), y3 = cadd(x3, x7);
        float2 t0 = csub(x0, x4), t1 = csub(x1, x5), t2 = csub(x2, x6), t3 = csub(x3, x7);
        float2 w8i = make_float2(-sg * w8.y, sg * w8.x);
        float2 z0 = cmul(w8, t0);
        float2 z1 = cmul(cmul(w8, e1), t1);
        float2 z2 = cmul(w8i, t2);
        float2 z3 = cmul(cmul(w8, e3), t3);
        {
            float2 a0 = cadd(y0, y2);
            float2 a2 = cmul(w4, csub(y0, y2));
            float2 a1 = cadd(y1, y3);
            float2 t = cmul(w4, csub(y1, y3));
            float2 a3 = make_float2(-sg * t.y, sg * t.x);
            d[swz(i0)]         = cadd(a0, a1);
            d[swz(i0 + M)]     = cmul(w2, csub(a0, a1));
            d[swz(i0 + 2 * M)] = cadd(a2, a3);
            d[swz(i0 + 3 * M)] = cmul(w2, csub(a2, a3));
        }
        {
            float2 a0 = cadd(z0, z2);
            float2 a2 = cmul(w4, csub(z0, z2));
            float2 a1 = cadd(z1, z3);
            float2 t = cmul(w4, csub(z1, z3));
            float2 a3 = make_float2(-sg * t.y, sg * t.x);
            d[swz(i0 + 4 * M)] = cadd(a0, a1);
            d[swz(i0 + 5 * M)] = cmul(w2, csub(a0, a1));
            d[swz(i0 + 6 * M)] = cadd(a2, a3);
            d[swz(i0 + 7 * M)] = cmul(w2, csub(a2, a3));
        }
    }
    __syncthreads();
}

template <int M>
__device__ __forceinline__ void dit_f8(float2* d, int N, int tid, int nt, float sg) {
    const float inv2m = 1.0f / (2.0f * (float)M);
    const float inv4m = 1.0f / (4.0f * (float)M);
    const float inv8m = 1.0f / (8.0f * (float)M);
    const float s2 = 0.70710678118654752f;
    for (int q = tid; q < (N >> 3); q += nt) {
        int j = q & (M - 1);
        int i0 = ((q & ~(M - 1)) << 3) + j;
        float2 x0 = d[swz(i0)],         x1 = d[swz(i0 + M)],
               x2 = d[swz(i0 + 2 * M)], x3 = d[swz(i0 + 3 * M)],
               x4 = d[swz(i0 + 4 * M)], x5 = d[swz(i0 + 5 * M)],
               x6 = d[swz(i0 + 6 * M)], x7 = d[swz(i0 + 7 * M)];
        float jf = (float)j;
        float2 wA = twid(jf * inv2m, sg);
        float2 wB = twid(jf * inv4m, sg);
        float2 wC = twid(jf * inv8m, sg);
        float2 t;
        t = cmul(wA, x1); float2 b0 = cadd(x0, t), b1 = csub(x0, t);
        t = cmul(wA, x3); float2 b2 = cadd(x2, t), b3 = csub(x2, t);
        t = cmul(wA, x5); float2 b4 = cadd(x4, t), b5 = csub(x4, t);
        t = cmul(wA, x7); float2 b6 = cadd(x6, t), b7 = csub(x6, t);
        float2 wBi = make_float2(-sg * wB.y, sg * wB.x);
        t = cmul(wB, b2);  float2 c0 = cadd(b0, t), c2 = csub(b0, t);
        t = cmul(wBi, b3); float2 c1 = cadd(b1, t), c3 = csub(b1, t);
        t = cmul(wB, b6);  float2 c4 = cadd(b4, t), c6 = csub(b4, t);
        t = cmul(wBi, b7); float2 c5 = cadd(b5, t), c7 = csub(b5, t);
        float2 e1 = make_float2(s2, sg * s2);
        float2 e3 = make_float2(-s2, sg * s2);
        float2 w1 = cmul(wC, e1);
        float2 w2_ = make_float2(-sg * wC.y, sg * wC.x);
        float2 w3 = cmul(wC, e3);
        t = cmul(wC, c4);  d[swz(i0)]         = cadd(c0, t); d[swz(i0 + 4 * M)] = csub(c0, t);
        t = cmul(w1, c5);  d[swz(i0 + M)]     = cadd(c1, t); d[swz(i0 + 5 * M)] = csub(c1, t);
        t = cmul(w2_, c6); d[swz(i0 + 2 * M)] = cadd(c2, t); d[swz(i0 + 6 * M)] = csub(c2, t);
        t = cmul(w3, c7);  d[swz(i0 + 3 * M)] = cadd(c3, t); d[swz(i0 + 7 * M)] = csub(c3, t);
    }
    __syncthreads();
}

// Stage 1 (r12 winner): cauchy 2pt (v11-real tables) ++ transpose-packed ++ skip.
__global__ __launch_bounds__(256, 8) void stage1_kernel(
    const float* __restrict__ u,
    const float* __restrict__ B_ri, const float* __restrict__ C_ri,
    const float* __restrict__ D,
    const float* __restrict__ Lambda_ri, const float* __restrict__ P_ri,
    const float* __restrict__ step,
    float2* __restrict__ at_g, float2* __restrict__ ut2, float* __restrict__ skip) {
    __shared__ float4 smem4[264];
    const int bid = blockIdx.x;
    const int tid = threadIdx.x;

    if (bid < CAU_BLOCKS) {
        float* v11f = (float*)(smem4 + 128);  // [64]
        const int h = bid >> 3;
        if (tid < NN) {
            int n = tid;
            float2 C = ((const float2*)C_ri)[h * NN + n];
            float2 Bv = ((const float2*)B_ri)[h * NN + n];
            float2 P = ((const float2*)P_ri)[h * NN + n];
            float2 lam = ((const float2*)Lambda_ri)[h * NN + n];
            float2 Cc = make_float2(C.x, -C.y);
            float2 Pc = make_float2(P.x, -P.y);
            float2 v00 = cmul(Cc, Bv);
            float2 v01 = cmul(Cc, P);
            float2 v10 = cmul(Pc, Bv);
            smem4[2 * n + 0] = make_float4(lam.x, lam.y, v00.x, v00.y);
            smem4[2 * n + 1] = make_float4(v01.x, v01.y, v10.x, v10.y);
            v11f[n] = P.x * P.x + P.y * P.y;
        }
        __syncthreads();

        const int lbase = ((bid & 7) << 8) | tid;  // [0, 2048)
        const float two_over_step = 2.0f / step[0];
        float gr[2], gi[2], ccx[2], ccy[2];
#pragma unroll
        for (int p = 0; p < 2; ++p) {
            int l = lbase + p * 2048;
            // libm sincosf: at l=2048 the fp32-pi inexactness keeps 1+z away from
            // exactly 0 (matches reference). DO NOT replace with HW sin/cos.
            double th = -6.283185307179586476925286766559 * (double)l / (double)LL;
            float sn, cs;
            sincosf((float)th, &sn, &cs);
            float dr = 1.0f + cs, di = sn;
            float inv = __builtin_amdgcn_rcpf(dr * dr + di * di);
            float nr = 1.0f - cs, ni = -sn;
            gr[p] = two_over_step * (nr * dr + ni * di) * inv;
            gi[p] = two_over_step * (ni * dr - nr * di) * inv;
            ccx[p] = 2.0f * dr * inv;
            ccy[p] = -2.0f * di * inv;
        }

        float2 k00[2], k01[2], k10[2], k11[2];
#pragma unroll
        for (int p = 0; p < 2; ++p) {
            k00[p] = make_float2(0.f, 0.f);
            k01[p] = make_float2(0.f, 0.f);
            k10[p] = make_float2(0.f, 0.f);
            k11[p] = make_float2(0.f, 0.f);
        }
#pragma unroll 4
        for (int n = 0; n < NN; ++n) {
            float4 tA = smem4[2 * n + 0];
            float4 tB = smem4[2 * n + 1];
            float w11 = v11f[n];
#pragma unroll
            for (int p = 0; p < 2; ++p) {
                float ar = gr[p] - tA.x, ai = gi[p] - tA.y;
                float id = __builtin_amdgcn_rcpf(ar * ar + ai * ai);
                float2 r = make_float2(ar * id, -ai * id);
                k00[p] = cadd(k00[p], cmul(make_float2(tA.z, tA.w), r));
                k01[p] = cadd(k01[p], cmul(make_float2(tB.x, tB.y), r));
                k10[p] = cadd(k10[p], cmul(make_float2(tB.z, tB.w), r));
                k11[p].x += w11 * r.x;
                k11[p].y += w11 * r.y;
            }
        }
#pragma unroll
        for (int p = 0; p < 2; ++p) {
            float wr = 1.0f + k11[p].x, wi = k11[p].y;
            float iw = __builtin_amdgcn_rcpf(wr * wr + wi * wi);
            float2 winv = make_float2(wr * iw, -wi * iw);
            float2 t = cmul(cmul(k01[p], winv), k10[p]);
            float2 at = cmul(make_float2(ccx[p], ccy[p]),
                             make_float2(k00[p].x - t.x, k00[p].y - t.y));
            at_g[(size_t)h * LL + lbase + p * 2048] = at;
        }
    } else if (bid < CAU_BLOCKS + TRU_BLOCKS) {
        float* tile = (float*)smem4;  // [32][33]
        int tb = bid - CAU_BLOCKS;
        int b = tb >> 9;
        int hq = (tb >> 7) & 3;
        int h0 = hq * 32;
        int l0 = (tb & 127) * 32;
        int tx = tid & 31, ty = tid >> 5;
        const float* up = u + (size_t)b * LL * HH;
        for (int i = ty; i < 32; i += 8)
            tile[i * 33 + tx] = up[(size_t)(l0 + i) * HH + h0 + tx];
        __syncthreads();
        float2* utp = ut2 + (size_t)b * 64 * LL;
#pragma unroll
        for (int i = ty; i < 16; i += 8) {
            int c = (h0 >> 1) + i;
            float2 v = make_float2(tile[tx * 33 + 2 * i], tile[tx * 33 + 2 * i + 1]);
            utp[(size_t)c * LL + l0 + tx] = v;
        }
    } else {
        int sb = bid - (CAU_BLOCKS + TRU_BLOCKS);
        int wid = tid >> 6, lane = tid & 63;
        int row = sb * 4 + wid;
        const float* ur = u + (size_t)row * HH;
        float v = ur[lane] * D[lane] + ur[lane + 64] * D[lane + 64];
        for (int off = 32; off > 0; off >>= 1) v += __shfl_down(v, off, 64);
        if (lane == 0) skip[row] = v;
    }
}

// Kernel A2: per h — scatter-load at -> IFFT4096 (dit_f8 x4) -> fused
// {scale+pad+head-r2} -> FFT8192 (dif_f8 x4) -> permuted K store KfP[h][t].
__global__ __launch_bounds__(1024) void kfreq_kernel(const float2* __restrict__ at_g,
                                                     float2* __restrict__ KfP) {
    __shared__ float2 sm[NFFT];  // 64 KB
    const int h = blockIdx.x;
    const int tid = threadIdx.x;
    const float2* ap = at_g + (size_t)h * LL;
#pragma unroll
    for (int it = 0; it < 4; ++it) {
        int t = tid + it * 1024;
        int l = ((t & 63) << 6) | (t >> 6);          // low6<->high6 swap
        sm[swz((int)(__brev((unsigned)l) >> 20))] = ap[l];
    }
    __syncthreads();

    dit_f8<1>(sm, 4096, tid, 1024, +1.f);
    dit_f8<8>(sm, 4096, tid, 1024, +1.f);
    dit_f8<64>(sm, 4096, tid, 1024, +1.f);
    dit_f8<512>(sm, 4096, tid, 1024, +1.f);

    const float inv8192 = 1.0f / 8192.0f;
    for (int t = tid; t < 4096; t += 1024) {
        float kv = sm[swz(t)].x * (1.0f / 4096.0f);
        float2 w = twid((float)t * inv8192, -1.f);
        sm[swz(t)] = make_float2(kv, 0.f);
        sm[swz(t + 4096)] = make_float2(kv * w.x, kv * w.y);
    }
    __syncthreads();

    dif_f8<512>(sm, 8192, tid, 1024, -1.f);
    dif_f8<64>(sm, 8192, tid, 1024, -1.f);
    dif_f8<8>(sm, 8192, tid, 1024, -1.f);
    dif_f8<1>(sm, 8192, tid, 1024, -1.f);

    float2* kfp = KfP + (size_t)h * KSTR;
    for (int t = tid; t <= 4096; t += 1024) kfp[t] = sm[swz(brev13(kkmap(t)))];
}

// Kernel C: two-for-one conv — packed float2 input, half2 output.
__global__ __launch_bounds__(1024) void conv_fft_kernel(const float2* __restrict__ ut2,
                                                        const float2* __restrict__ KfP,
                                                        __half2* __restrict__ yt2) {
    __shared__ float2 sm[NFFT];  // 64 KB
    const int b = blockIdx.x >> 6;
    const int c = blockIdx.x & 63;
    const int h0 = 2 * c, h1 = 2 * c + 1;
    const int tid = threadIdx.x;
    const float2* up2 = ut2 + ((size_t)b * 64 + c) * LL;
    const float inv8192 = 1.0f / 8192.0f;

    // fused load + head radix-2 DIF stage (upper half of input is zero)
    for (int i = tid; i < 4096; i += 1024) {
        float2 a = up2[i];
        float2 w = twid((float)i * inv8192, -1.f);
        sm[swz(i)] = a;
        sm[swz(i + 4096)] = cmul(w, a);
    }
    __syncthreads();

    dif_f8<512>(sm, 8192, tid, 1024, -1.f);
    dif_f8<64>(sm, 8192, tid, 1024, -1.f);
    dif_f8<8>(sm, 8192, tid, 1024, -1.f);
    dif_f8<1>(sm, 8192, tid, 1024, -1.f);

    const float2* kf0 = KfP + (size_t)h0 * KSTR;
    const float2* kf1 = KfP + (size_t)h1 * KSTR;
    for (int t = tid; t <= 4096; t += 1024) {
        int kk = kkmap(t);
        bool self = (kk == 0) || (kk == 4096);
        int p = swz(brev13(kk));
        int q = self ? p : swz(brev13(NFFT - kk));
        float2 K0 = kf0[t];
        float2 K1 = kf1[t];
        float2 Zp = sm[p];
        float2 Zq = sm[q];
        float2 U0 = make_float2(0.5f * (Zp.x + Zq.x), 0.5f * (Zp.y - Zq.y));
        float2 U1 = make_float2(0.5f * (Zp.y + Zq.y), 0.5f * (Zq.x - Zp.x));
        float2 A = cmul(U0, K0);
        float2 C = cmul(U1, K1);
        sm[p] = make_float2(A.x - C.y, A.y + C.x);             // W[k]   = A + iC
        if (!self) sm[q] = make_float2(A.x + C.y, C.x - A.y);  // W[N-k] = conj(A - iC)
    }
    __syncthreads();

    dit_f8<1>(sm, 8192, tid, 1024, +1.f);
    dit_f8<8>(sm, 8192, tid, 1024, +1.f);
    dit_f8<64>(sm, 8192, tid, 1024, +1.f);
    dit_f8<512>(sm, 8192, tid, 1024, +1.f);

    // fused tail radix-2 DIT stage + 1/N scale + packed half2 store
    __half2* yp = yt2 + ((size_t)b * 64 + c) * LL;
    const float invN = 1.0f / (float)NFFT;
    for (int x = tid; x < 4096; x += 1024) {
        float2 w = twid((float)x * inv8192, +1.f);
        float2 a = sm[swz(x)];
        float2 bb = cmul(w, sm[swz(x + 4096)]);
        yp[x] = __floats2half2_rn((a.x + bb.x) * invN, (a.y + bb.y) * invN);
    }
}

// Kernel D: transpose yt2 [B,64,L] (half2) -> y [B,L,H] fp32, add skip[b,l].
__global__ __launch_bounds__(256) void transpose_y_kernel(const __half2* __restrict__ yt2,
                                                          const float* __restrict__ skip,
                                                          float* __restrict__ y) {
    __shared__ __half2 tile[32 * 17];
    int b = blockIdx.z;
    int c0 = blockIdx.x * 16;  // 16 half2 pairs = 32 h
    int l0 = blockIdx.y * 32;
    int tx = threadIdx.x, ty = threadIdx.y;  // 32 x 8
    const __half2* ytp = yt2 + (size_t)b * 64 * LL;
    const float* skp = skip + (size_t)b * LL;
    float* yp = y + (size_t)b * LL * HH;
    for (int i = ty; i < 16; i += 8)
        tile[tx * 17 + i] = ytp[(size_t)(c0 + i) * LL + l0 + tx];
    __syncthreads();
    int h0 = c0 * 2;
    for (int i = ty; i < 32; i += 8) {
        int l = l0 + i;
        float sk = skp[l];
        float2 f = __half22float2(tile[i * 17 + (tx >> 1)]);
        float v = (tx & 1) ? f.y : f.x;
        yp[(size_t)l * HH + h0 + tx] = v + sk;
    }
}

extern "C" void kernel_launch(void* const* d_in, const int* in_sizes, int n_in,
                              void* d_out, int out_size, void* d_ws, size_t ws_size,
                              hipStream_t stream) {
    const float* u = (const float*)d_in[0];
    const float* B_ri = (const float*)d_in[1];
    const float* C_ri = (const float*)d_in[2];
    const float* D = (const float*)d_in[3];
    const float* Lambda_ri = (const float*)d_in[4];
    const float* P_ri = (const float*)d_in[5];
    const float* step = (const float*)d_in[6];
    float* out = (float*)d_out;

    char* ws = (char*)d_ws;
    float2* KfP = (float2*)ws;                              // ~4.2 MB @ 0
    float* skip = (float*)(ws + (size_t)6 * 1024 * 1024);   // 128 KB @ 6 MB
    float2* ut2 = (float2*)(ws + (size_t)8 * 1024 * 1024);  // 16 MB @ 8 MB
    char* hi = ws + (size_t)24 * 1024 * 1024;               // 8 MB region @ 24 MB
    // at_g (4 MB) aliases the yt2 region: written by stage1, consumed by kfreq
    // before conv overwrites it with yt2 (stream-serial).
    float2* at_g = (float2*)hi;
    __half2* yt2 = (__half2*)hi;

    stage1_kernel<<<dim3(CAU_BLOCKS + TRU_BLOCKS + SKP_BLOCKS), dim3(256), 0, stream>>>(
        u, B_ri, C_ri, D, Lambda_ri, P_ri, step, at_g, ut2, skip);
    kfreq_kernel<<<dim3(HH), dim3(1024), 0, stream>>>(at_g, KfP);
    conv_fft_kernel<<<dim3(BB * HH / 2), dim3(1024), 0, stream>>>(ut2, KfP, yt2);
    transpose_y_kernel<<<dim3(HH / 32, LL / 32, BB), dim3(32, 8), 0, stream>>>(yt2, skip, out);
}